// Round 2
// baseline (308.140 us; speedup 1.0000x reference)
//
#include <hip/hip_runtime.h>

// Problem constants (from reference)
// LAYER_IDX = [0, 4096, 6144, 7168, 7680, 7682]
// layer1: s=4096 dim=2048 ebase=0       (no LN on input)
// layer2: s=6144 dim=1024 ebase=262144  (LN over 2048 src nodes)
// layer3: s=7168 dim=512  ebase=393216  (LN over 1024 src nodes)
// out:    s=7680 dim=2    ebase=458752  (LN over 512 src nodes)
#define BATCH 512
#define IN_DIM 4096
#define FAN_IN 128
#define EPS 1e-5f

// ---------------------------------------------------------------------------
// x [B, IN_DIM] row-major -> acts [IN_DIM, B] node-major (32x32 LDS tiles).
// Block (0,0) additionally zeroes the LN stats scratch (3 x (sum+sumsq)[512]).
__global__ void transpose_x(const float* __restrict__ x, float* __restrict__ acts,
                            float* __restrict__ stats) {
    __shared__ float tile[32][33];  // +1 pad breaks bank conflicts
    const int tx = threadIdx.x;     // 0..31
    const int ty = threadIdx.y;     // 0..7
    if (blockIdx.x == 0 && blockIdx.y == 0) {
        const int t = ty * 32 + tx;
        for (int i = t; i < 3 * 2 * BATCH; i += 256) stats[i] = 0.0f;
    }
    const int f0 = blockIdx.x * 32;
    const int b0 = blockIdx.y * 32;
#pragma unroll
    for (int i = 0; i < 32; i += 8)
        tile[ty + i][tx] = x[(size_t)(b0 + ty + i) * IN_DIM + f0 + tx];
    __syncthreads();
#pragma unroll
    for (int i = 0; i < 32; i += 8)
        acts[(size_t)(f0 + ty + i) * BATCH + b0 + tx] = tile[tx][ty + i];
}

// ---------------------------------------------------------------------------
// Fused gather (+ optional LN+ReLU applied to SOURCE reads) (+ optional LN
// stats contribution for this layer's outputs via atomics).
// Block = 256 threads = 2 nodes x 128 lanes; each lane owns 4 batch columns
// (float4). Edges for both nodes (256 = 2*FAN_IN) staged in LDS.
template <bool LN_IN>
__global__ __launch_bounds__(256) void gather(
    float* __restrict__ acts,
    const float* __restrict__ weight,
    const int* __restrict__ edge_src,
    const float* __restrict__ bias,
    const float* __restrict__ gamma,
    const float* __restrict__ beta,
    const float* __restrict__ statsIn,   // finalized sum/sumsq of source layer
    float* __restrict__ statsOut,        // this layer's stats accumulator (or null)
    int s, int ebase, float invDimIn) {
    __shared__ float w_s[2 * FAN_IN];
    __shared__ int   src_s[2 * FAN_IN];
    __shared__ float g_s[2 * FAN_IN];
    __shared__ float bt_s[2 * FAN_IN];
    __shared__ float red_sum[BATCH];
    __shared__ float red_sq[BATCH];

    const int tid = threadIdx.x;
    const int eb = ebase + blockIdx.x * (2 * FAN_IN);
    {
        w_s[tid] = weight[eb + tid];
        const int sc = edge_src[eb + tid];
        src_s[tid] = sc;
        if (LN_IN) {
            g_s[tid]  = gamma[sc - IN_DIM];
            bt_s[tid] = beta[sc - IN_DIM];
        }
    }
    __syncthreads();

    const int nodeLocal = tid >> 7;   // 0 or 1
    const int lane = tid & 127;
    const int b4 = lane * 4;
    const int kb = nodeLocal * FAN_IN;

    float4 mean = {0, 0, 0, 0}, rstd = {0, 0, 0, 0};
    if (LN_IN) {
        const float4 s1 = *(const float4*)(statsIn + b4);
        const float4 s2 = *(const float4*)(statsIn + BATCH + b4);
        mean.x = s1.x * invDimIn; mean.y = s1.y * invDimIn;
        mean.z = s1.z * invDimIn; mean.w = s1.w * invDimIn;
        rstd.x = rsqrtf(s2.x * invDimIn - mean.x * mean.x + EPS);
        rstd.y = rsqrtf(s2.y * invDimIn - mean.y * mean.y + EPS);
        rstd.z = rsqrtf(s2.z * invDimIn - mean.z * mean.z + EPS);
        rstd.w = rsqrtf(s2.w * invDimIn - mean.w * mean.w + EPS);
    }

    float4 acc = {0, 0, 0, 0};
#pragma unroll 8
    for (int k = 0; k < FAN_IN; ++k) {
        const float w = w_s[kb + k];
        const float4 v = *(const float4*)(acts + (size_t)src_s[kb + k] * BATCH + b4);
        if (LN_IN) {
            const float g = g_s[kb + k];
            const float bt = bt_s[kb + k];
            acc.x += w * fmaxf(fmaf(g * (v.x - mean.x), rstd.x, bt), 0.0f);
            acc.y += w * fmaxf(fmaf(g * (v.y - mean.y), rstd.y, bt), 0.0f);
            acc.z += w * fmaxf(fmaf(g * (v.z - mean.z), rstd.z, bt), 0.0f);
            acc.w += w * fmaxf(fmaf(g * (v.w - mean.w), rstd.w, bt), 0.0f);
        } else {
            acc.x += w * v.x;
            acc.y += w * v.y;
            acc.z += w * v.z;
            acc.w += w * v.w;
        }
    }

    const int node = s + blockIdx.x * 2 + nodeLocal;
    const float bv = bias[node - IN_DIM];
    float4 ov;
    ov.x = acc.x + bv; ov.y = acc.y + bv; ov.z = acc.z + bv; ov.w = acc.w + bv;
    *(float4*)(acts + (size_t)node * BATCH + b4) = ov;

    if (statsOut != nullptr) {
        // Combine the block's two nodes in LDS, then one atomic per address.
        if (nodeLocal == 1) {
            red_sum[b4 + 0] = ov.x; red_sum[b4 + 1] = ov.y;
            red_sum[b4 + 2] = ov.z; red_sum[b4 + 3] = ov.w;
            red_sq[b4 + 0] = ov.x * ov.x; red_sq[b4 + 1] = ov.y * ov.y;
            red_sq[b4 + 2] = ov.z * ov.z; red_sq[b4 + 3] = ov.w * ov.w;
        }
        __syncthreads();
        if (nodeLocal == 0) {
            atomicAdd(&statsOut[b4 + 0], ov.x + red_sum[b4 + 0]);
            atomicAdd(&statsOut[b4 + 1], ov.y + red_sum[b4 + 1]);
            atomicAdd(&statsOut[b4 + 2], ov.z + red_sum[b4 + 2]);
            atomicAdd(&statsOut[b4 + 3], ov.w + red_sum[b4 + 3]);
            atomicAdd(&statsOut[BATCH + b4 + 0], ov.x * ov.x + red_sq[b4 + 0]);
            atomicAdd(&statsOut[BATCH + b4 + 1], ov.y * ov.y + red_sq[b4 + 1]);
            atomicAdd(&statsOut[BATCH + b4 + 2], ov.z * ov.z + red_sq[b4 + 2]);
            atomicAdd(&statsOut[BATCH + b4 + 3], ov.w * ov.w + red_sq[b4 + 3]);
        }
    }
}

// ---------------------------------------------------------------------------
// Output layer: 2 nodes, LN+ReLU on layer-3 sources, writes d_out [B, 2].
// Single block: 2 nodes x 128 lanes x 4 cols.
__global__ __launch_bounds__(256) void gather_out(
    const float* __restrict__ acts,
    const float* __restrict__ weight,
    const int* __restrict__ edge_src,
    const float* __restrict__ bias,
    const float* __restrict__ gamma,
    const float* __restrict__ beta,
    const float* __restrict__ statsIn,
    float* __restrict__ out) {
    __shared__ float w_s[2 * FAN_IN];
    __shared__ int   src_s[2 * FAN_IN];
    __shared__ float g_s[2 * FAN_IN];
    __shared__ float bt_s[2 * FAN_IN];

    const int tid = threadIdx.x;
    const int eb = 458752 + tid;   // output layer edge base
    {
        w_s[tid] = weight[eb];
        const int sc = edge_src[eb];
        src_s[tid] = sc;
        g_s[tid]  = gamma[sc - IN_DIM];
        bt_s[tid] = beta[sc - IN_DIM];
    }
    __syncthreads();

    const int j = tid >> 7;           // output node 0/1
    const int lane = tid & 127;
    const int b4 = lane * 4;
    const int kb = j * FAN_IN;
    const float invDim = 1.0f / 512.0f;

    const float4 s1 = *(const float4*)(statsIn + b4);
    const float4 s2 = *(const float4*)(statsIn + BATCH + b4);
    float4 mean, rstd;
    mean.x = s1.x * invDim; mean.y = s1.y * invDim;
    mean.z = s1.z * invDim; mean.w = s1.w * invDim;
    rstd.x = rsqrtf(s2.x * invDim - mean.x * mean.x + EPS);
    rstd.y = rsqrtf(s2.y * invDim - mean.y * mean.y + EPS);
    rstd.z = rsqrtf(s2.z * invDim - mean.z * mean.z + EPS);
    rstd.w = rsqrtf(s2.w * invDim - mean.w * mean.w + EPS);

    float4 acc = {0, 0, 0, 0};
#pragma unroll 8
    for (int k = 0; k < FAN_IN; ++k) {
        const float w = w_s[kb + k];
        const float4 v = *(const float4*)(acts + (size_t)src_s[kb + k] * BATCH + b4);
        const float g = g_s[kb + k];
        const float bt = bt_s[kb + k];
        acc.x += w * fmaxf(fmaf(g * (v.x - mean.x), rstd.x, bt), 0.0f);
        acc.y += w * fmaxf(fmaf(g * (v.y - mean.y), rstd.y, bt), 0.0f);
        acc.z += w * fmaxf(fmaf(g * (v.z - mean.z), rstd.z, bt), 0.0f);
        acc.w += w * fmaxf(fmaf(g * (v.w - mean.w), rstd.w, bt), 0.0f);
    }

    const float bv = bias[(7680 + j) - IN_DIM];
    out[(size_t)(b4 + 0) * 2 + j] = acc.x + bv;
    out[(size_t)(b4 + 1) * 2 + j] = acc.y + bv;
    out[(size_t)(b4 + 2) * 2 + j] = acc.z + bv;
    out[(size_t)(b4 + 3) * 2 + j] = acc.w + bv;
}

// ---------------------------------------------------------------------------
extern "C" void kernel_launch(void* const* d_in, const int* in_sizes, int n_in,
                              void* d_out, int out_size, void* d_ws, size_t ws_size,
                              hipStream_t stream) {
    const float* x        = (const float*)d_in[0];  // [512, 4096]
    const float* weight   = (const float*)d_in[1];  // [459008]
    const float* bias     = (const float*)d_in[2];  // [3586]
    const float* ln_gamma = (const float*)d_in[3];  // [3584]
    const float* ln_beta  = (const float*)d_in[4];  // [3584]
    const int*   edge_src = (const int*)d_in[5];    // [459008]
    // d_in[6] = edge_tgt: implicit (edges contiguous per target node).
    float* out = (float*)d_out;

    // Workspace: acts [7680 x 512] fp32, then 3 x (sum[512]+sumsq[512]).
    float* acts  = (float*)d_ws;
    float* stats = acts + (size_t)7680 * BATCH;
    float* st1 = stats;          // layer-1 outputs (dim 2048)
    float* st2 = stats + 1024;   // layer-2 outputs (dim 1024)
    float* st3 = stats + 2048;   // layer-3 outputs (dim 512)

    transpose_x<<<dim3(IN_DIM / 32, BATCH / 32), dim3(32, 8), 0, stream>>>(x, acts, stats);

    // Layer 1: 4096 -> 2048 (no LN on inputs; emit stats for layer-1 outputs)
    gather<false><<<1024, 256, 0, stream>>>(acts, weight, edge_src, bias,
                                            ln_gamma, ln_beta, nullptr, st1,
                                            4096, 0, 0.0f);
    // Layer 2: 2048 -> 1024 (LN+ReLU on sources via st1; emit st2)
    gather<true><<<512, 256, 0, stream>>>(acts, weight, edge_src, bias,
                                          ln_gamma, ln_beta, st1, st2,
                                          6144, 262144, 1.0f / 2048.0f);
    // Layer 3: 1024 -> 512 (LN+ReLU via st2; emit st3)
    gather<true><<<256, 256, 0, stream>>>(acts, weight, edge_src, bias,
                                          ln_gamma, ln_beta, st2, st3,
                                          7168, 393216, 1.0f / 1024.0f);
    // Output: 512 -> 2 (LN+ReLU via st3), writes d_out [B, 2]
    gather_out<<<1, 256, 0, stream>>>(acts, weight, edge_src, bias,
                                      ln_gamma, ln_beta, st3, out);
}

// Round 3
// 246.042 us; speedup vs baseline: 1.2524x; 1.2524x over previous
//
#include <hip/hip_runtime.h>

// LAYER_IDX = [0, 4096, 6144, 7168, 7680, 7682]
// layer1: 4096->2048  ebase 0       | layer2: 2048->1024 ebase 262144
// layer3: 1024->512   ebase 393216  | out: 512->2        ebase 458752
#define BATCH 512
#define IN_DIM 4096
#define FAN_IN 128
#define EPS 1e-5f

typedef unsigned short u16;
typedef unsigned int u32;
typedef __attribute__((ext_vector_type(8))) short short8;   // 8 bf16 (4 VGPRs)
typedef __attribute__((ext_vector_type(4))) float f32x4;

__device__ inline u16 f2bf(float f) {   // fp32 -> bf16, round-nearest-even
    union { float f; u32 u; } v; v.f = f;
    u32 r = v.u + 0x7fffu + ((v.u >> 16) & 1u);
    return (u16)(r >> 16);
}

// ---------------------------------------------------------------------------
// Densify sparse weights -> bf16 dense rows. One block per target node.
// Edges of node t are contiguous [ebase + t*128, +128); duplicates accumulate
// via LDS atomics (matches segment_sum). Blocks 0-2 also zero the LN stats.
__global__ __launch_bounds__(256) void densify(
    const float* __restrict__ weight, const int* __restrict__ edge_src,
    u16* __restrict__ Wd, float* __restrict__ stats) {
    __shared__ float row[4096];
    const int bid = blockIdx.x;
    const int tid = threadIdx.x;
    if (bid < 3) {  // zero 3 x (sum[512]+sumsq[512])
        for (int i = tid; i < 1024; i += 256) stats[bid * 1024 + i] = 0.0f;
    }
    int Kin, ebase, srcbase; u16* outrow;
    if (bid < 2048)      { Kin = 4096; ebase = bid * 128;                srcbase = 0;    outrow = Wd + (size_t)bid * 4096; }
    else if (bid < 3072) { int t = bid - 2048; Kin = 2048; ebase = 262144 + t * 128; srcbase = 4096; outrow = Wd + 8388608 + (size_t)t * 2048; }
    else                 { int t = bid - 3072; Kin = 1024; ebase = 393216 + t * 128; srcbase = 6144; outrow = Wd + 10485760 + (size_t)t * 1024; }
    for (int k = tid; k < Kin; k += 256) row[k] = 0.0f;
    __syncthreads();
    if (tid < FAN_IN)
        atomicAdd(&row[edge_src[ebase + tid] - srcbase], weight[ebase + tid]);
    __syncthreads();
    for (int k = tid; k < Kin; k += 256) outrow[k] = f2bf(row[k]);
}

// ---------------------------------------------------------------------------
// C[M x 512] = W[M x K](bf16) x B[K x 512] + bias, fp32 out (node-major),
// + per-column (batch) sum/sumsq atomics for the NEXT layer's LN.
// XB=true : Bsrc is x, fp32 batch-major [n][K] (row stride K), no LN.
// XB=false: Bsrc is raw fp32 act node-major [k][512]; LN+ReLU applied on load.
// Block: 256 thr = 4 waves of 32x32; tile 64M x 64N, BK=32.
template <bool XB>
__global__ __launch_bounds__(256) void gemm64(
    const u16* __restrict__ W, const float* __restrict__ Bsrc,
    float* __restrict__ Cout, const float* __restrict__ bias_l,
    const float* __restrict__ gamma_l, const float* __restrict__ beta_l,
    const float* __restrict__ statsIn, float* __restrict__ statsOut,
    int K, float invDimIn) {
    __shared__ u16 As[64 * 40];   // [m][k] stride 40 (80 B, 16B-aligned rows)
    __shared__ u16 Bs[64 * 40];   // [n][k] stride 40
    __shared__ float redS[64], redQ[64];

    const int tid = threadIdx.x;
    const int wave = tid >> 6, lane = tid & 63;
    const int quad = lane >> 4, l15 = lane & 15;
    const int m_off = (wave & 1) * 32, n_off = (wave >> 1) * 32;
    const int m0 = blockIdx.x * 64, n0 = blockIdx.y * 64;

    // B-staging thread mapping (fixed per thread)
    const int sn = XB ? (tid >> 2) : (tid & 63);   // batch column this thread stages
    const int sc = XB ? (tid & 3) : (tid >> 6);    // chunk / k-group

    float mean_n = 0.f, rstd_n = 0.f;
    if (!XB) {  // LN params for staged column sn (constant across K-loop)
        const float s1 = statsIn[n0 + sn], s2 = statsIn[BATCH + n0 + sn];
        mean_n = s1 * invDimIn;
        rstd_n = rsqrtf(s2 * invDimIn - mean_n * mean_n + EPS);
    }

    f32x4 acc[2][2] = {};
    const int am = tid >> 2, ac = tid & 3;   // A-staging: row, 8-elem chunk

    for (int k0 = 0; k0 < K; k0 += 32) {
        __syncthreads();
        // ---- stage A: 64 x 32 bf16, already bf16 in global
        *(uint4*)(As + am * 40 + ac * 8) =
            *(const uint4*)(W + (size_t)(m0 + am) * K + k0 + ac * 8);
        // ---- stage B: 64 n x 32 k, transposed into [n][k]
        if (XB) {
            const float* rp = Bsrc + (size_t)(n0 + sn) * K + k0 + sc * 8;
            const float4 f0 = *(const float4*)rp;
            const float4 f1 = *(const float4*)(rp + 4);
            uint4 pk;
            pk.x = f2bf(f0.x) | ((u32)f2bf(f0.y) << 16);
            pk.y = f2bf(f0.z) | ((u32)f2bf(f0.w) << 16);
            pk.z = f2bf(f1.x) | ((u32)f2bf(f1.y) << 16);
            pk.w = f2bf(f1.z) | ((u32)f2bf(f1.w) << 16);
            *(uint4*)(Bs + sn * 40 + sc * 8) = pk;
        } else {
#pragma unroll
            for (int p = 0; p < 2; ++p) {
                const int kb = p * 16 + sc * 4;
                u16 pk[4];
#pragma unroll
                for (int r = 0; r < 4; ++r) {
                    const int kk = k0 + kb + r;
                    float v = Bsrc[(size_t)kk * BATCH + n0 + sn];
                    v = fmaf(gamma_l[kk] * (v - mean_n), rstd_n, beta_l[kk]);
                    pk[r] = f2bf(fmaxf(v, 0.0f));
                }
                *(uint2*)(Bs + sn * 40 + kb) = *(const uint2*)pk;
            }
        }
        __syncthreads();
        // ---- fragments + 4 MFMAs (2 m-tiles x 2 n-tiles)
        short8 a0 = *(const short8*)(As + (m_off + l15) * 40 + quad * 8);
        short8 a1 = *(const short8*)(As + (m_off + 16 + l15) * 40 + quad * 8);
        short8 b0 = *(const short8*)(Bs + (n_off + l15) * 40 + quad * 8);
        short8 b1 = *(const short8*)(Bs + (n_off + 16 + l15) * 40 + quad * 8);
        acc[0][0] = __builtin_amdgcn_mfma_f32_16x16x32_bf16(a0, b0, acc[0][0], 0, 0, 0);
        acc[0][1] = __builtin_amdgcn_mfma_f32_16x16x32_bf16(a0, b1, acc[0][1], 0, 0, 0);
        acc[1][0] = __builtin_amdgcn_mfma_f32_16x16x32_bf16(a1, b0, acc[1][0], 0, 0, 0);
        acc[1][1] = __builtin_amdgcn_mfma_f32_16x16x32_bf16(a1, b1, acc[1][1], 0, 0, 0);
    }

    // ---- epilogue: bias, store raw fp32 C, per-column stats
    float cs[2] = {0.f, 0.f}, cq[2] = {0.f, 0.f};
#pragma unroll
    for (int i = 0; i < 2; ++i) {
        const int mg = m0 + m_off + i * 16 + quad * 4;
#pragma unroll
        for (int r = 0; r < 4; ++r) {
            const float bv = bias_l[mg + r];
#pragma unroll
            for (int j = 0; j < 2; ++j) {
                const int ng = n0 + n_off + j * 16 + l15;
                const float v = acc[i][j][r] + bv;
                Cout[(size_t)(mg + r) * BATCH + ng] = v;
                cs[j] += v; cq[j] += v * v;
            }
        }
    }
    __syncthreads();
    if (tid < 64) { redS[tid] = 0.f; redQ[tid] = 0.f; }
    __syncthreads();
#pragma unroll
    for (int j = 0; j < 2; ++j) {
        atomicAdd(&redS[n_off + j * 16 + l15], cs[j]);
        atomicAdd(&redQ[n_off + j * 16 + l15], cq[j]);
    }
    __syncthreads();
    if (tid < 64) {
        atomicAdd(&statsOut[n0 + tid], redS[tid]);
        atomicAdd(&statsOut[BATCH + n0 + tid], redQ[tid]);
    }
}

// ---------------------------------------------------------------------------
// Output layer: sparse gather of 2 nodes over layer-3 acts (raw fp32 +
// on-the-fly LN/ReLU). Single block; lanes = 2 nodes x 128 x float4 cols.
__global__ __launch_bounds__(256) void gather_out(
    const float* __restrict__ act3,         // [512 x 512] local rows 0..511
    const float* __restrict__ weight,
    const int* __restrict__ edge_src,
    const float* __restrict__ bias,
    const float* __restrict__ gamma_l,      // ln_gamma + 3072
    const float* __restrict__ beta_l,
    const float* __restrict__ statsIn,      // st3
    float* __restrict__ out) {
    __shared__ float w_s[256]; __shared__ int src_s[256];
    __shared__ float g_s[256]; __shared__ float bt_s[256];
    const int tid = threadIdx.x;
    {
        const int eb = 458752 + tid;
        w_s[tid] = weight[eb];
        const int sl = edge_src[eb] - 7168;   // local layer-3 row
        src_s[tid] = sl;
        g_s[tid] = gamma_l[sl]; bt_s[tid] = beta_l[sl];
    }
    __syncthreads();
    const int j = tid >> 7, lane = tid & 127, b4 = lane * 4, kb = j * FAN_IN;
    const float invDim = 1.0f / 512.0f;
    const float4 s1 = *(const float4*)(statsIn + b4);
    const float4 s2 = *(const float4*)(statsIn + BATCH + b4);
    float4 mean, rstd;
    mean.x = s1.x * invDim; mean.y = s1.y * invDim;
    mean.z = s1.z * invDim; mean.w = s1.w * invDim;
    rstd.x = rsqrtf(s2.x * invDim - mean.x * mean.x + EPS);
    rstd.y = rsqrtf(s2.y * invDim - mean.y * mean.y + EPS);
    rstd.z = rsqrtf(s2.z * invDim - mean.z * mean.z + EPS);
    rstd.w = rsqrtf(s2.w * invDim - mean.w * mean.w + EPS);
    float4 acc = {0, 0, 0, 0};
#pragma unroll 8
    for (int k = 0; k < FAN_IN; ++k) {
        const float w = w_s[kb + k], g = g_s[kb + k], bt = bt_s[kb + k];
        const float4 v = *(const float4*)(act3 + (size_t)src_s[kb + k] * BATCH + b4);
        acc.x += w * fmaxf(fmaf(g * (v.x - mean.x), rstd.x, bt), 0.0f);
        acc.y += w * fmaxf(fmaf(g * (v.y - mean.y), rstd.y, bt), 0.0f);
        acc.z += w * fmaxf(fmaf(g * (v.z - mean.z), rstd.z, bt), 0.0f);
        acc.w += w * fmaxf(fmaf(g * (v.w - mean.w), rstd.w, bt), 0.0f);
    }
    const float bv = bias[3584 + j];
    out[(size_t)(b4 + 0) * 2 + j] = acc.x + bv;
    out[(size_t)(b4 + 1) * 2 + j] = acc.y + bv;
    out[(size_t)(b4 + 2) * 2 + j] = acc.z + bv;
    out[(size_t)(b4 + 3) * 2 + j] = acc.w + bv;
}

// ---------------------------------------------------------------------------
extern "C" void kernel_launch(void* const* d_in, const int* in_sizes, int n_in,
                              void* d_out, int out_size, void* d_ws, size_t ws_size,
                              hipStream_t stream) {
    const float* x        = (const float*)d_in[0];  // [512, 4096] batch-major
    const float* weight   = (const float*)d_in[1];
    const float* bias     = (const float*)d_in[2];
    const float* ln_gamma = (const float*)d_in[3];
    const float* ln_beta  = (const float*)d_in[4];
    const int*   edge_src = (const int*)d_in[5];
    float* out = (float*)d_out;

    // ws: act1[2048x512] act2[1024x512] act3[512x512] fp32 | stats 3x1024 | Wd bf16
    float* act1  = (float*)d_ws;
    float* act2  = act1 + (size_t)2048 * 512;
    float* act3  = act2 + (size_t)1024 * 512;
    float* stats = act3 + (size_t)512 * 512;
    u16*   Wd    = (u16*)(stats + 3 * 1024);
    float* st1 = stats, *st2 = stats + 1024, *st3 = stats + 2048;

    // 1) densify weights (+ zero stats)
    densify<<<3584, 256, 0, stream>>>(weight, edge_src, Wd, stats);
    // 2) G1: [2048x4096] x x^T -> act1 (+st1)
    gemm64<true><<<dim3(32, 8), 256, 0, stream>>>(
        Wd, x, act1, bias, nullptr, nullptr, nullptr, st1, 4096, 0.0f);
    // 3) G2: LN(act1) -> act2 (+st2)
    gemm64<false><<<dim3(16, 8), 256, 0, stream>>>(
        Wd + 8388608, act1, act2, bias + 2048, ln_gamma, ln_beta,
        st1, st2, 2048, 1.0f / 2048.0f);
    // 4) G3: LN(act2) -> act3 (+st3)
    gemm64<false><<<dim3(8, 8), 256, 0, stream>>>(
        Wd + 10485760, act2, act3, bias + 3072, ln_gamma + 2048, ln_beta + 2048,
        st2, st3, 1024, 1.0f / 1024.0f);
    // 5) output layer (sparse, 2 nodes) -> d_out [512, 2]
    gather_out<<<1, 256, 0, stream>>>(act3, weight, edge_src, bias,
                                      ln_gamma + 3072, ln_beta + 3072, st3, out);
}

// Round 4
// 181.155 us; speedup vs baseline: 1.7010x; 1.3582x over previous
//
#include <hip/hip_runtime.h>

// LAYER_IDX = [0, 4096, 6144, 7168, 7680, 7682]
// layer1: 4096->2048 ebase 0       | layer2: 2048->1024 ebase 262144
// layer3: 1024->512  ebase 393216  | out: 512->2        ebase 458752
#define BATCH 512
#define FAN_IN 128
#define EPS 1e-5f

typedef unsigned short u16;
typedef unsigned int u32;
typedef __attribute__((ext_vector_type(8))) short short8;   // 8 bf16
typedef __attribute__((ext_vector_type(4))) float f32x4;

__device__ __forceinline__ u16 f2bf(float f) {   // fp32->bf16 RNE
    union { float f; u32 u; } v; v.f = f;
    u32 r = v.u + 0x7fffu + ((v.u >> 16) & 1u);
    return (u16)(r >> 16);
}
__device__ __forceinline__ float bf2f(u16 h) {
    union { u32 u; float f; } v; v.u = ((u32)h) << 16; return v.f;
}
__device__ __forceinline__ void ld16(const void* g, void* l) {  // async global->LDS 16B
    __builtin_amdgcn_global_load_lds(
        (const __attribute__((address_space(1))) u32*)g,
        (__attribute__((address_space(3))) u32*)l, 16, 0, 0);
}

// ---------------------------------------------------------------------------
// prep: densify W (bf16 [m][k]); x -> bf16 [n][k]; zero acts + stats.
__global__ __launch_bounds__(256) void prep(
    const float* __restrict__ weight, const int* __restrict__ edge_src,
    const float* __restrict__ x,
    u16* __restrict__ Wd, u16* __restrict__ xb,
    float* __restrict__ acts, float* __restrict__ stats) {
    __shared__ float row[4096];
    const int bid = blockIdx.x, t = threadIdx.x;
    if (bid < 3584) {  // densify one target node
        int Kin, ebase, srcbase; u16* outrow;
        if (bid < 2048)      { Kin = 4096; ebase = bid * 128;                 srcbase = 0;    outrow = Wd + (size_t)bid * 4096; }
        else if (bid < 3072) { int q = bid - 2048; Kin = 2048; ebase = 262144 + q * 128; srcbase = 4096; outrow = Wd + 8388608  + (size_t)q * 2048; }
        else                 { int q = bid - 3072; Kin = 1024; ebase = 393216 + q * 128; srcbase = 6144; outrow = Wd + 10485760 + (size_t)q * 1024; }
        for (int k = t; k < Kin; k += 256) row[k] = 0.f;
        __syncthreads();
        if (t < FAN_IN)
            atomicAdd(&row[edge_src[ebase + t] - srcbase], weight[ebase + t]);
        __syncthreads();
        for (int k0 = t * 8; k0 < Kin; k0 += 2048) {
            u16 pk[8];
#pragma unroll
            for (int i = 0; i < 8; ++i) pk[i] = f2bf(row[k0 + i]);
            *(uint4*)(outrow + k0) = *(const uint4*)pk;
        }
    } else if (bid < 4096) {  // x row -> bf16
        const int b = bid - 3584;
        const float* xr = x + (size_t)b * 4096;
        u16* xo = xb + (size_t)b * 4096;
        for (int k0 = t * 8; k0 < 4096; k0 += 2048) {
            const float4 f0 = *(const float4*)(xr + k0);
            const float4 f1 = *(const float4*)(xr + k0 + 4);
            uint4 pk;
            pk.x = f2bf(f0.x) | ((u32)f2bf(f0.y) << 16);
            pk.y = f2bf(f0.z) | ((u32)f2bf(f0.w) << 16);
            pk.z = f2bf(f1.x) | ((u32)f2bf(f1.y) << 16);
            pk.w = f2bf(f1.z) | ((u32)f2bf(f1.w) << 16);
            *(uint4*)(xo + k0) = pk;
        }
    } else if (bid < 4992) {  // zero act1/2/3: 896 blocks x 2048 floats
        const float4 z = {0, 0, 0, 0};
        float* p = acts + (size_t)(bid - 4096) * 2048 + t * 8;
        *(float4*)p = z; *(float4*)(p + 4) = z;
    } else {                  // zero stats
        for (int i = t; i < 3072; i += 256) stats[i] = 0.f;
    }
}

// ---------------------------------------------------------------------------
// C[M x 512] = A[M x K] * Bb[512 x K]^T  (both bf16, k-contiguous rows),
// + bias, fp32 C node-major, + fused per-batch-column sum/sumsq atomics.
// 64x64 tile, BK=64, dbuf LDS via global_load_lds, XOR-swizzled chunks.
__global__ __launch_bounds__(256) void gemm_bt(
    const u16* __restrict__ A, const u16* __restrict__ Bb,
    float* __restrict__ C, const float* __restrict__ bias_l,
    float* __restrict__ statsOut, int K) {
    __shared__ u16 sA[2][4096];   // [buf][row*64 + chunk*8], chunk swizzled
    __shared__ u16 sB[2][4096];
    __shared__ float redS[64], redQ[64];

    const int tid = threadIdx.x;
    const int m0 = blockIdx.x * 64, n0 = blockIdx.y * 64;

    // staging: thread owns slots tid and tid+256 (slot = row*8 + lds_chunk)
    const int r1 = tid >> 3, c1 = tid & 7;
    const int g1 = c1 ^ (r1 & 7);
    const int r2 = r1 + 32, g2 = c1 ^ (r2 & 7);
    const u16* gA1 = A + (size_t)(m0 + r1) * K + g1 * 8;
    const u16* gA2 = A + (size_t)(m0 + r2) * K + g2 * 8;
    const u16* gB1 = Bb + (size_t)(n0 + r1) * K + g1 * 8;
    const u16* gB2 = Bb + (size_t)(n0 + r2) * K + g2 * 8;
    const int lo1 = tid * 8, lo2 = tid * 8 + 2048;

    // fragment LDS offsets (u16 units), conflict-free via swizzle
    const int wave = tid >> 6, lane = tid & 63;
    const int l15 = lane & 15, quad = lane >> 4;
    const int moff = (wave & 1) * 32, noff = (wave >> 1) * 32;
    const int sw = l15 & 7;
    int offA[2][2], offB[2][2];
#pragma unroll
    for (int i = 0; i < 2; ++i)
#pragma unroll
        for (int h = 0; h < 2; ++h) {
            const int ch = ((h * 4 + quad) ^ sw) * 8;
            offA[i][h] = (moff + i * 16 + l15) * 64 + ch;
            offB[i][h] = (noff + i * 16 + l15) * 64 + ch;
        }

    f32x4 acc[2][2] = {};
    const int niter = K >> 6;

    // prologue: stage buf 0
    ld16(gA1, &sA[0][lo1]); ld16(gA2, &sA[0][lo2]);
    ld16(gB1, &sB[0][lo1]); ld16(gB2, &sB[0][lo2]);

    for (int it = 0; it < niter; ++it) {
        __syncthreads();  // drains this buf's loads; frees other buf for prefetch
        if (it + 1 < niter) {
            const int k0 = (it + 1) << 6;
            const int nb = (it + 1) & 1;
            ld16(gA1 + k0, &sA[nb][lo1]); ld16(gA2 + k0, &sA[nb][lo2]);
            ld16(gB1 + k0, &sB[nb][lo1]); ld16(gB2 + k0, &sB[nb][lo2]);
        }
        const u16* a = sA[it & 1];
        const u16* b = sB[it & 1];
#pragma unroll
        for (int h = 0; h < 2; ++h) {
            const short8 a0 = *(const short8*)(a + offA[0][h]);
            const short8 a1 = *(const short8*)(a + offA[1][h]);
            const short8 b0 = *(const short8*)(b + offB[0][h]);
            const short8 b1 = *(const short8*)(b + offB[1][h]);
            acc[0][0] = __builtin_amdgcn_mfma_f32_16x16x32_bf16(a0, b0, acc[0][0], 0, 0, 0);
            acc[0][1] = __builtin_amdgcn_mfma_f32_16x16x32_bf16(a0, b1, acc[0][1], 0, 0, 0);
            acc[1][0] = __builtin_amdgcn_mfma_f32_16x16x32_bf16(a1, b0, acc[1][0], 0, 0, 0);
            acc[1][1] = __builtin_amdgcn_mfma_f32_16x16x32_bf16(a1, b1, acc[1][1], 0, 0, 0);
        }
    }

    // epilogue: bias, store fp32 C [m][n], fused column stats
    float cs[2] = {0.f, 0.f}, cq[2] = {0.f, 0.f};
#pragma unroll
    for (int i = 0; i < 2; ++i) {
        const int mg = m0 + moff + i * 16 + quad * 4;
#pragma unroll
        for (int r = 0; r < 4; ++r) {
            const float bv = bias_l[mg + r];
#pragma unroll
            for (int j = 0; j < 2; ++j) {
                const int ng = n0 + noff + j * 16 + l15;
                const float v = acc[i][j][r] + bv;
                C[(size_t)(mg + r) * BATCH + ng] = v;
                cs[j] += v; cq[j] += v * v;
            }
        }
    }
    __syncthreads();
    if (tid < 64) { redS[tid] = 0.f; redQ[tid] = 0.f; }
    __syncthreads();
#pragma unroll
    for (int j = 0; j < 2; ++j) {
        atomicAdd(&redS[noff + j * 16 + l15], cs[j]);
        atomicAdd(&redQ[noff + j * 16 + l15], cq[j]);
    }
    __syncthreads();
    if (tid < 64) {
        atomicAdd(&statsOut[n0 + tid], redS[tid]);
        atomicAdd(&statsOut[BATCH + n0 + tid], redQ[tid]);
    }
}

// ---------------------------------------------------------------------------
// LN+ReLU apply + transpose: act fp32 [M][512] -> actb bf16 [512][M].
// 32x32 tiles; grid (M/32, 16).
__global__ __launch_bounds__(256) void lnapply(
    const float* __restrict__ act, const float* __restrict__ st,
    const float* __restrict__ gamma_l, const float* __restrict__ beta_l,
    u16* __restrict__ actb, int M, float invDim) {
    __shared__ u16 tile[32][40];
    const int t = threadIdx.x;
    const int m0 = blockIdx.x * 32, n0 = blockIdx.y * 32;
    {
        const int m = t >> 3, nq = t & 7;
        const float4 v = *(const float4*)(act + (size_t)(m0 + m) * BATCH + n0 + nq * 4);
        const float g = gamma_l[m0 + m], bt = beta_l[m0 + m];
        const float4 s1 = *(const float4*)(st + n0 + nq * 4);
        const float4 s2 = *(const float4*)(st + BATCH + n0 + nq * 4);
        float mn[4], rs[4];
        mn[0] = s1.x * invDim; mn[1] = s1.y * invDim; mn[2] = s1.z * invDim; mn[3] = s1.w * invDim;
        rs[0] = rsqrtf(s2.x * invDim - mn[0] * mn[0] + EPS);
        rs[1] = rsqrtf(s2.y * invDim - mn[1] * mn[1] + EPS);
        rs[2] = rsqrtf(s2.z * invDim - mn[2] * mn[2] + EPS);
        rs[3] = rsqrtf(s2.w * invDim - mn[3] * mn[3] + EPS);
        const float vv[4] = {v.x, v.y, v.z, v.w};
#pragma unroll
        for (int i = 0; i < 4; ++i)
            tile[nq * 4 + i][m] = f2bf(fmaxf(fmaf(g * (vv[i] - mn[i]), rs[i], bt), 0.0f));
    }
    __syncthreads();
    {
        const int n = t >> 3, mq = t & 7;
        u16 o[4];
#pragma unroll
        for (int i = 0; i < 4; ++i) o[i] = tile[n][mq * 4 + i];
        *(uint2*)(actb + (size_t)(n0 + n) * M + m0 + mq * 4) = *(const uint2*)o;
    }
}

// ---------------------------------------------------------------------------
// Output layer: 2 nodes from post-LN bf16 actb3 [512][512]. grid 4 x 256.
__global__ __launch_bounds__(256) void outk(
    const u16* __restrict__ actb3, const float* __restrict__ weight,
    const int* __restrict__ edge_src, const float* __restrict__ bias,
    float* __restrict__ out) {
    __shared__ float w_s[256]; __shared__ int s_s[256];
    const int t = threadIdx.x;
    w_s[t] = weight[458752 + t];
    s_s[t] = edge_src[458752 + t] - 7168;
    __syncthreads();
    const int g = blockIdx.x * 256 + t;   // 0..1023
    const int b = g >> 1, j = g & 1;
    const u16* rowp = actb3 + (size_t)b * 512;
    const int kb = j * FAN_IN;
    float acc = 0.f;
#pragma unroll 8
    for (int k = 0; k < FAN_IN; ++k)
        acc += w_s[kb + k] * bf2f(rowp[s_s[kb + k]]);
    out[(size_t)b * 2 + j] = acc + bias[3584 + j];
}

// ---------------------------------------------------------------------------
extern "C" void kernel_launch(void* const* d_in, const int* in_sizes, int n_in,
                              void* d_out, int out_size, void* d_ws, size_t ws_size,
                              hipStream_t stream) {
    const float* x        = (const float*)d_in[0];
    const float* weight   = (const float*)d_in[1];
    const float* bias     = (const float*)d_in[2];
    const float* ln_gamma = (const float*)d_in[3];
    const float* ln_beta  = (const float*)d_in[4];
    const int*   edge_src = (const int*)d_in[5];
    float* out = (float*)d_out;

    // ws layout (fp32 units):
    float* act1  = (float*)d_ws;                       // [2048 x 512]
    float* act2  = act1 + (size_t)2048 * 512;          // [1024 x 512]
    float* act3  = act2 + (size_t)1024 * 512;          // [512 x 512]
    float* stats = act3 + (size_t)512 * 512;           // 3 x 1024
    u16*   xb    = (u16*)(stats + 3072);               // [512 x 4096] bf16
    u16*   actb1 = xb + (size_t)512 * 4096;            // [512 x 2048]
    u16*   actb2 = actb1 + (size_t)512 * 2048;         // [512 x 1024]
    u16*   actb3 = actb2 + (size_t)512 * 1024;         // [512 x 512]
    u16*   Wd    = actb3 + (size_t)512 * 512;          // 11534336 bf16
    float* st1 = stats, *st2 = stats + 1024, *st3 = stats + 2048;

    prep<<<4993, 256, 0, stream>>>(weight, edge_src, x, Wd, xb, act1, stats);

    // G1: [2048x4096] x xb^T -> act1 (+st1)
    gemm_bt<<<dim3(32, 8), 256, 0, stream>>>(Wd, xb, act1, bias, st1, 4096);
    lnapply<<<dim3(64, 16), 256, 0, stream>>>(act1, st1, ln_gamma, ln_beta,
                                              actb1, 2048, 1.0f / 2048.0f);
    // G2: [1024x2048] x actb1^T -> act2 (+st2)
    gemm_bt<<<dim3(16, 8), 256, 0, stream>>>(Wd + 8388608, actb1, act2,
                                             bias + 2048, st2, 2048);
    lnapply<<<dim3(32, 16), 256, 0, stream>>>(act2, st2, ln_gamma + 2048,
                                              ln_beta + 2048, actb2, 1024,
                                              1.0f / 1024.0f);
    // G3: [512x1024] x actb2^T -> act3 (+st3)
    gemm_bt<<<dim3(8, 8), 256, 0, stream>>>(Wd + 10485760, actb2, act3,
                                            bias + 3072, st3, 1024);
    lnapply<<<dim3(16, 16), 256, 0, stream>>>(act3, st3, ln_gamma + 3072,
                                              ln_beta + 3072, actb3, 512,
                                              1.0f / 512.0f);
    // Output layer -> d_out [512, 2]
    outk<<<4, 256, 0, stream>>>(actb3, weight, edge_src, bias, out);
}

// Round 5
// 168.223 us; speedup vs baseline: 1.8317x; 1.0769x over previous
//
#include <hip/hip_runtime.h>

// LAYER_IDX = [0, 4096, 6144, 7168, 7680, 7682]
// layer1: 4096->2048 ebase 0       | layer2: 2048->1024 ebase 262144
// layer3: 1024->512  ebase 393216  | out: 512->2        ebase 458752
#define BATCH 512
#define FAN_IN 128
#define EPS 1e-5f

typedef unsigned short u16;
typedef unsigned int u32;
typedef __attribute__((ext_vector_type(8))) short short8;   // 8 bf16
typedef __attribute__((ext_vector_type(4))) float f32x4;

__device__ __forceinline__ u16 f2bf(float f) {   // fp32->bf16 RNE
    union { float f; u32 u; } v; v.f = f;
    u32 r = v.u + 0x7fffu + ((v.u >> 16) & 1u);
    return (u16)(r >> 16);
}
__device__ __forceinline__ float bf2f(u16 h) {
    union { u32 u; float f; } v; v.u = ((u32)h) << 16; return v.f;
}
__device__ __forceinline__ void ld16(const void* g, void* l) {  // async global->LDS 16B
    __builtin_amdgcn_global_load_lds(
        (const __attribute__((address_space(1))) u32*)g,
        (__attribute__((address_space(3))) u32*)l, 16, 0, 0);
}

// ---------------------------------------------------------------------------
// prep: densify W (bf16 [m][k]); x -> bf16 [n][k]; zero acts + stats.
__global__ __launch_bounds__(256) void prep(
    const float* __restrict__ weight, const int* __restrict__ edge_src,
    const float* __restrict__ x,
    u16* __restrict__ Wd, u16* __restrict__ xb,
    float* __restrict__ acts, float* __restrict__ stats) {
    __shared__ float row[4096];
    const int bid = blockIdx.x, t = threadIdx.x;
    if (bid < 3584) {  // densify one target node
        int Kin, ebase, srcbase; u16* outrow;
        if (bid < 2048)      { Kin = 4096; ebase = bid * 128;                 srcbase = 0;    outrow = Wd + (size_t)bid * 4096; }
        else if (bid < 3072) { int q = bid - 2048; Kin = 2048; ebase = 262144 + q * 128; srcbase = 4096; outrow = Wd + 8388608  + (size_t)q * 2048; }
        else                 { int q = bid - 3072; Kin = 1024; ebase = 393216 + q * 128; srcbase = 6144; outrow = Wd + 10485760 + (size_t)q * 1024; }
        for (int k = t; k < Kin; k += 256) row[k] = 0.f;
        __syncthreads();
        if (t < FAN_IN)
            atomicAdd(&row[edge_src[ebase + t] - srcbase], weight[ebase + t]);
        __syncthreads();
        for (int k0 = t * 8; k0 < Kin; k0 += 2048) {
            u16 pk[8];
#pragma unroll
            for (int i = 0; i < 8; ++i) pk[i] = f2bf(row[k0 + i]);
            *(uint4*)(outrow + k0) = *(const uint4*)pk;
        }
    } else if (bid < 4096) {  // x row -> bf16
        const int b = bid - 3584;
        const float* xr = x + (size_t)b * 4096;
        u16* xo = xb + (size_t)b * 4096;
        for (int k0 = t * 8; k0 < 4096; k0 += 2048) {
            const float4 f0 = *(const float4*)(xr + k0);
            const float4 f1 = *(const float4*)(xr + k0 + 4);
            uint4 pk;
            pk.x = f2bf(f0.x) | ((u32)f2bf(f0.y) << 16);
            pk.y = f2bf(f0.z) | ((u32)f2bf(f0.w) << 16);
            pk.z = f2bf(f1.x) | ((u32)f2bf(f1.y) << 16);
            pk.w = f2bf(f1.z) | ((u32)f2bf(f1.w) << 16);
            *(uint4*)(xo + k0) = pk;
        }
    } else if (bid < 4992) {  // zero act1/2/3 (needed: K-split accumulates atomically)
        const float4 z = {0, 0, 0, 0};
        float* p = acts + (size_t)(bid - 4096) * 2048 + t * 8;
        *(float4*)p = z; *(float4*)(p + 4) = z;
    } else {                  // zero stats
        for (int i = t; i < 3072; i += 256) stats[i] = 0.f;
    }
}

// ---------------------------------------------------------------------------
// C[M x 512] += A[M x Kc] * Bb[512 x Kc]^T  (bf16, k-contiguous rows) for this
// block's K-chunk (blockIdx.z); chunk 0 adds bias. fp32 atomic accumulate.
// 64x64 tile, BK=32, dbuf LDS via global_load_lds, 8-perm XOR swizzle.
__global__ __launch_bounds__(256, 8) void gemm_bt(
    const u16* __restrict__ A, const u16* __restrict__ Bb,
    float* __restrict__ C, const float* __restrict__ bias_l,
    int K, int kchunk) {
    __shared__ u16 sA[2][2048];   // [buf][row*32 + chunk*8]
    __shared__ u16 sB[2][2048];

    const int tid = threadIdx.x;
    const int m0 = blockIdx.x * 64, n0 = blockIdx.y * 64;
    const int kbase = blockIdx.z * kchunk;

    // staging: thread tid owns LDS slot tid (16 B). slot = row*4 + c holds
    // global chunk q = c ^ sw(row), sw(row) = (row ^ (row>>2)) & 3.
    const int r = tid >> 2, c = tid & 3;
    const int q = c ^ ((r ^ (r >> 2)) & 3);
    const u16* gA = A + (size_t)(m0 + r) * K + kbase + q * 8;
    const u16* gB = Bb + (size_t)(n0 + r) * K + kbase + q * 8;
    const int lo = tid * 8;   // u16 units

    const int wave = tid >> 6, lane = tid & 63;
    const int l15 = lane & 15, quad = lane >> 4;
    const int moff = (wave & 1) * 32, noff = (wave >> 1) * 32;
    int offA[2], offB[2];
#pragma unroll
    for (int i = 0; i < 2; ++i) {
        const int ra = moff + i * 16 + l15;
        offA[i] = ra * 32 + ((quad ^ ((ra ^ (ra >> 2)) & 3)) * 8);
        const int rb = noff + i * 16 + l15;
        offB[i] = rb * 32 + ((quad ^ ((rb ^ (rb >> 2)) & 3)) * 8);
    }

    f32x4 acc[2][2] = {};
    const int niter = kchunk >> 5;

    ld16(gA, &sA[0][lo]); ld16(gB, &sB[0][lo]);
    for (int it = 0; it < niter; ++it) {
        __syncthreads();
        if (it + 1 < niter) {
            const int k0 = (it + 1) << 5;
            const int nb = (it + 1) & 1;
            ld16(gA + k0, &sA[nb][lo]); ld16(gB + k0, &sB[nb][lo]);
        }
        const u16* a = sA[it & 1];
        const u16* b = sB[it & 1];
        const short8 a0 = *(const short8*)(a + offA[0]);
        const short8 a1 = *(const short8*)(a + offA[1]);
        const short8 b0 = *(const short8*)(b + offB[0]);
        const short8 b1 = *(const short8*)(b + offB[1]);
        acc[0][0] = __builtin_amdgcn_mfma_f32_16x16x32_bf16(a0, b0, acc[0][0], 0, 0, 0);
        acc[0][1] = __builtin_amdgcn_mfma_f32_16x16x32_bf16(a0, b1, acc[0][1], 0, 0, 0);
        acc[1][0] = __builtin_amdgcn_mfma_f32_16x16x32_bf16(a1, b0, acc[1][0], 0, 0, 0);
        acc[1][1] = __builtin_amdgcn_mfma_f32_16x16x32_bf16(a1, b1, acc[1][1], 0, 0, 0);
    }

    // epilogue: atomic-accumulate partial (chunk 0 adds bias)
    const bool first = (blockIdx.z == 0);
#pragma unroll
    for (int i = 0; i < 2; ++i) {
        const int mg = m0 + moff + i * 16 + quad * 4;
#pragma unroll
        for (int rr = 0; rr < 4; ++rr) {
            const float bv = first ? bias_l[mg + rr] : 0.0f;
#pragma unroll
            for (int j = 0; j < 2; ++j) {
                const int ng = n0 + noff + j * 16 + l15;
                atomicAdd(&C[(size_t)(mg + rr) * BATCH + ng], acc[i][j][rr] + bv);
            }
        }
    }
}

// ---------------------------------------------------------------------------
// Column stats: per batch column n, sum & sumsq over M rows of fp32 C.
// grid M/32; block: 256 thr, thread t owns cols 2t, 2t+1 over 32 rows.
__global__ __launch_bounds__(256) void stats_k(
    const float* __restrict__ C, float* __restrict__ st) {
    const int t = threadIdx.x;
    const float* p = C + (size_t)(blockIdx.x * 32) * BATCH + t * 2;
    float s0 = 0.f, q0 = 0.f, s1 = 0.f, q1 = 0.f;
#pragma unroll 8
    for (int m = 0; m < 32; ++m) {
        const float2 v = *(const float2*)(p + (size_t)m * BATCH);
        s0 += v.x; q0 += v.x * v.x;
        s1 += v.y; q1 += v.y * v.y;
    }
    atomicAdd(&st[t * 2], s0);
    atomicAdd(&st[t * 2 + 1], s1);
    atomicAdd(&st[BATCH + t * 2], q0);
    atomicAdd(&st[BATCH + t * 2 + 1], q1);
}

// ---------------------------------------------------------------------------
// LN+ReLU apply + transpose: act fp32 [M][512] -> actb bf16 [512][M].
__global__ __launch_bounds__(256) void lnapply(
    const float* __restrict__ act, const float* __restrict__ st,
    const float* __restrict__ gamma_l, const float* __restrict__ beta_l,
    u16* __restrict__ actb, int M, float invDim) {
    __shared__ u16 tile[32][40];
    const int t = threadIdx.x;
    const int m0 = blockIdx.x * 32, n0 = blockIdx.y * 32;
    {
        const int m = t >> 3, nq = t & 7;
        const float4 v = *(const float4*)(act + (size_t)(m0 + m) * BATCH + n0 + nq * 4);
        const float g = gamma_l[m0 + m], bt = beta_l[m0 + m];
        const float4 s1 = *(const float4*)(st + n0 + nq * 4);
        const float4 s2 = *(const float4*)(st + BATCH + n0 + nq * 4);
        float mn[4], rs[4];
        mn[0] = s1.x * invDim; mn[1] = s1.y * invDim; mn[2] = s1.z * invDim; mn[3] = s1.w * invDim;
        rs[0] = rsqrtf(s2.x * invDim - mn[0] * mn[0] + EPS);
        rs[1] = rsqrtf(s2.y * invDim - mn[1] * mn[1] + EPS);
        rs[2] = rsqrtf(s2.z * invDim - mn[2] * mn[2] + EPS);
        rs[3] = rsqrtf(s2.w * invDim - mn[3] * mn[3] + EPS);
        const float vv[4] = {v.x, v.y, v.z, v.w};
#pragma unroll
        for (int i = 0; i < 4; ++i)
            tile[nq * 4 + i][m] = f2bf(fmaxf(fmaf(g * (vv[i] - mn[i]), rs[i], bt), 0.0f));
    }
    __syncthreads();
    {
        const int n = t >> 3, mq = t & 7;
        u16 o[4];
#pragma unroll
        for (int i = 0; i < 4; ++i) o[i] = tile[n][mq * 4 + i];
        *(uint2*)(actb + (size_t)(n0 + n) * M + m0 + mq * 4) = *(const uint2*)o;
    }
}

// ---------------------------------------------------------------------------
// Output layer: 2 nodes from post-LN bf16 actb3 [512][512]. grid 4 x 256.
__global__ __launch_bounds__(256) void outk(
    const u16* __restrict__ actb3, const float* __restrict__ weight,
    const int* __restrict__ edge_src, const float* __restrict__ bias,
    float* __restrict__ out) {
    __shared__ float w_s[256]; __shared__ int s_s[256];
    const int t = threadIdx.x;
    w_s[t] = weight[458752 + t];
    s_s[t] = edge_src[458752 + t] - 7168;
    __syncthreads();
    const int g = blockIdx.x * 256 + t;   // 0..1023
    const int b = g >> 1, j = g & 1;
    const u16* rowp = actb3 + (size_t)b * 512;
    const int kb = j * FAN_IN;
    float acc = 0.f;
#pragma unroll 8
    for (int k = 0; k < FAN_IN; ++k)
        acc += w_s[kb + k] * bf2f(rowp[s_s[kb + k]]);
    out[(size_t)b * 2 + j] = acc + bias[3584 + j];
}

// ---------------------------------------------------------------------------
extern "C" void kernel_launch(void* const* d_in, const int* in_sizes, int n_in,
                              void* d_out, int out_size, void* d_ws, size_t ws_size,
                              hipStream_t stream) {
    const float* x        = (const float*)d_in[0];
    const float* weight   = (const float*)d_in[1];
    const float* bias     = (const float*)d_in[2];
    const float* ln_gamma = (const float*)d_in[3];
    const float* ln_beta  = (const float*)d_in[4];
    const int*   edge_src = (const int*)d_in[5];
    float* out = (float*)d_out;

    float* act1  = (float*)d_ws;                       // [2048 x 512]
    float* act2  = act1 + (size_t)2048 * 512;          // [1024 x 512]
    float* act3  = act2 + (size_t)1024 * 512;          // [512 x 512]
    float* stats = act3 + (size_t)512 * 512;           // 3 x 1024
    u16*   xb    = (u16*)(stats + 3072);               // [512 x 4096] bf16
    u16*   actb1 = xb + (size_t)512 * 4096;            // [512 x 2048]
    u16*   actb2 = actb1 + (size_t)512 * 2048;         // [512 x 1024]
    u16*   actb3 = actb2 + (size_t)512 * 1024;         // [512 x 512]
    u16*   Wd    = actb3 + (size_t)512 * 512;          // 11534336 bf16
    float* st1 = stats, *st2 = stats + 1024, *st3 = stats + 2048;

    prep<<<4993, 256, 0, stream>>>(weight, edge_src, x, Wd, xb, act1, stats);

    // G1: [2048x4096] x xb^T -> act1 (K-split 4)
    gemm_bt<<<dim3(32, 8, 4), 256, 0, stream>>>(Wd, xb, act1, bias, 4096, 1024);
    stats_k<<<64, 256, 0, stream>>>(act1, st1);
    lnapply<<<dim3(64, 16), 256, 0, stream>>>(act1, st1, ln_gamma, ln_beta,
                                              actb1, 2048, 1.0f / 2048.0f);
    // G2: [1024x2048] x actb1^T -> act2
    gemm_bt<<<dim3(16, 8, 4), 256, 0, stream>>>(Wd + 8388608, actb1, act2,
                                                bias + 2048, 2048, 512);
    stats_k<<<32, 256, 0, stream>>>(act2, st2);
    lnapply<<<dim3(32, 16), 256, 0, stream>>>(act2, st2, ln_gamma + 2048,
                                              ln_beta + 2048, actb2, 1024,
                                              1.0f / 1024.0f);
    // G3: [512x1024] x actb2^T -> act3
    gemm_bt<<<dim3(8, 8, 4), 256, 0, stream>>>(Wd + 10485760, actb2, act3,
                                               bias + 3072, 1024, 256);
    stats_k<<<16, 256, 0, stream>>>(act3, st3);
    lnapply<<<dim3(16, 16), 256, 0, stream>>>(act3, st3, ln_gamma + 3072,
                                              ln_beta + 3072, actb3, 512,
                                              1.0f / 512.0f);
    // Output layer -> d_out [512, 2]
    outk<<<4, 256, 0, stream>>>(actb3, weight, edge_src, bias, out);
}

// Round 6
// 160.900 us; speedup vs baseline: 1.9151x; 1.0455x over previous
//
#include <hip/hip_runtime.h>

// LAYER_IDX = [0, 4096, 6144, 7168, 7680, 7682]
// layer1: 4096->2048 ebase 0       | layer2: 2048->1024 ebase 262144
// layer3: 1024->512  ebase 393216  | out: 512->2        ebase 458752
#define BATCH 512
#define FAN_IN 128
#define EPS 1e-5f

typedef unsigned short u16;
typedef unsigned int u32;
typedef __attribute__((ext_vector_type(8))) short short8;   // 8 bf16
typedef __attribute__((ext_vector_type(4))) float f32x4;

__device__ __forceinline__ u16 f2bf(float f) {   // fp32->bf16 RNE
    union { float f; u32 u; } v; v.f = f;
    u32 r = v.u + 0x7fffu + ((v.u >> 16) & 1u);
    return (u16)(r >> 16);
}
__device__ __forceinline__ float bf2f(u16 h) {
    union { u32 u; float f; } v; v.u = ((u32)h) << 16; return v.f;
}
__device__ __forceinline__ void ld16(const void* g, void* l) {  // async global->LDS 16B
    __builtin_amdgcn_global_load_lds(
        (const __attribute__((address_space(1))) u32*)g,
        (__attribute__((address_space(3))) u32*)l, 16, 0, 0);
}

// ---------------------------------------------------------------------------
// prep: densify W (bf16 [m][k]); x -> bf16 [n][k]; zero stats.
// (No act zeroing: K-split partials are plain-stored, every element written.)
__global__ __launch_bounds__(256) void prep(
    const float* __restrict__ weight, const int* __restrict__ edge_src,
    const float* __restrict__ x,
    u16* __restrict__ Wd, u16* __restrict__ xb, float* __restrict__ stats) {
    __shared__ float row[4096];
    const int bid = blockIdx.x, t = threadIdx.x;
    if (bid < 3584) {  // densify one target node
        int Kin, ebase, srcbase; u16* outrow;
        if (bid < 2048)      { Kin = 4096; ebase = bid * 128;                 srcbase = 0;    outrow = Wd + (size_t)bid * 4096; }
        else if (bid < 3072) { int q = bid - 2048; Kin = 2048; ebase = 262144 + q * 128; srcbase = 4096; outrow = Wd + 8388608  + (size_t)q * 2048; }
        else                 { int q = bid - 3072; Kin = 1024; ebase = 393216 + q * 128; srcbase = 6144; outrow = Wd + 10485760 + (size_t)q * 1024; }
        for (int k = t; k < Kin; k += 256) row[k] = 0.f;
        __syncthreads();
        if (t < FAN_IN)
            atomicAdd(&row[edge_src[ebase + t] - srcbase], weight[ebase + t]);
        __syncthreads();
        for (int k0 = t * 8; k0 < Kin; k0 += 2048) {
            u16 pk[8];
#pragma unroll
            for (int i = 0; i < 8; ++i) pk[i] = f2bf(row[k0 + i]);
            *(uint4*)(outrow + k0) = *(const uint4*)pk;
        }
    } else if (bid < 4096) {  // x row -> bf16
        const int b = bid - 3584;
        const float* xr = x + (size_t)b * 4096;
        u16* xo = xb + (size_t)b * 4096;
        for (int k0 = t * 8; k0 < 4096; k0 += 2048) {
            const float4 f0 = *(const float4*)(xr + k0);
            const float4 f1 = *(const float4*)(xr + k0 + 4);
            uint4 pk;
            pk.x = f2bf(f0.x) | ((u32)f2bf(f0.y) << 16);
            pk.y = f2bf(f0.z) | ((u32)f2bf(f0.w) << 16);
            pk.z = f2bf(f1.x) | ((u32)f2bf(f1.y) << 16);
            pk.w = f2bf(f1.z) | ((u32)f2bf(f1.w) << 16);
            *(uint4*)(xo + k0) = pk;
        }
    } else {                  // zero stats (reduce_stats atomics need 0 base)
        for (int i = t; i < 3072; i += 256) stats[i] = 0.f;
    }
}

// ---------------------------------------------------------------------------
// Partial GEMM: Cz[blockIdx.z][M x 512] = A[M x Kc] * Bb[512 x Kc]^T for this
// block's K-chunk. Plain stores (no atomics, no init required).
// 64x64 tile, BK=32, dbuf LDS via global_load_lds, XOR swizzle.
__global__ __launch_bounds__(256, 8) void gemm_bt(
    const u16* __restrict__ A, const u16* __restrict__ Bb,
    float* __restrict__ Cz, int M, int K, int kchunk) {
    __shared__ u16 sA[2][2048];   // [buf][row*32 + chunk*8]
    __shared__ u16 sB[2][2048];

    const int tid = threadIdx.x;
    const int m0 = blockIdx.x * 64, n0 = blockIdx.y * 64;
    const int kbase = blockIdx.z * kchunk;
    float* Cp = Cz + (size_t)blockIdx.z * M * BATCH;

    // staging: thread tid owns LDS slot tid (16 B); slot (row,c) holds global
    // chunk q = c ^ sw(row), sw(row) = (row ^ (row>>2)) & 3.
    const int r = tid >> 2, c = tid & 3;
    const int q = c ^ ((r ^ (r >> 2)) & 3);
    const u16* gA = A + (size_t)(m0 + r) * K + kbase + q * 8;
    const u16* gB = Bb + (size_t)(n0 + r) * K + kbase + q * 8;
    const int lo = tid * 8;   // u16 units

    const int wave = tid >> 6, lane = tid & 63;
    const int l15 = lane & 15, quad = lane >> 4;
    const int moff = (wave & 1) * 32, noff = (wave >> 1) * 32;
    int offA[2], offB[2];
#pragma unroll
    for (int i = 0; i < 2; ++i) {
        const int ra = moff + i * 16 + l15;
        offA[i] = ra * 32 + ((quad ^ ((ra ^ (ra >> 2)) & 3)) * 8);
        const int rb = noff + i * 16 + l15;
        offB[i] = rb * 32 + ((quad ^ ((rb ^ (rb >> 2)) & 3)) * 8);
    }

    f32x4 acc[2][2] = {};
    const int niter = kchunk >> 5;

    ld16(gA, &sA[0][lo]); ld16(gB, &sB[0][lo]);
    for (int it = 0; it < niter; ++it) {
        __syncthreads();
        if (it + 1 < niter) {
            const int k0 = (it + 1) << 5;
            const int nb = (it + 1) & 1;
            ld16(gA + k0, &sA[nb][lo]); ld16(gB + k0, &sB[nb][lo]);
        }
        const u16* a = sA[it & 1];
        const u16* b = sB[it & 1];
        const short8 a0 = *(const short8*)(a + offA[0]);
        const short8 a1 = *(const short8*)(a + offA[1]);
        const short8 b0 = *(const short8*)(b + offB[0]);
        const short8 b1 = *(const short8*)(b + offB[1]);
        acc[0][0] = __builtin_amdgcn_mfma_f32_16x16x32_bf16(a0, b0, acc[0][0], 0, 0, 0);
        acc[0][1] = __builtin_amdgcn_mfma_f32_16x16x32_bf16(a0, b1, acc[0][1], 0, 0, 0);
        acc[1][0] = __builtin_amdgcn_mfma_f32_16x16x32_bf16(a1, b0, acc[1][0], 0, 0, 0);
        acc[1][1] = __builtin_amdgcn_mfma_f32_16x16x32_bf16(a1, b1, acc[1][1], 0, 0, 0);
    }

    // epilogue: plain partial stores
#pragma unroll
    for (int i = 0; i < 2; ++i) {
        const int mg = m0 + moff + i * 16 + quad * 4;
#pragma unroll
        for (int rr = 0; rr < 4; ++rr) {
#pragma unroll
            for (int j = 0; j < 2; ++j) {
                const int ng = n0 + noff + j * 16 + l15;
                Cp[(size_t)(mg + rr) * BATCH + ng] = acc[i][j][rr];
            }
        }
    }
}

// ---------------------------------------------------------------------------
// Sum 4 K-partials + bias -> final fp32 C; fused column sum/sumsq stats
// (block-reduced registers -> few global atomics). grid M/16; thread t owns
// columns 2t, 2t+1. All loads fully coalesced.
__global__ __launch_bounds__(256) void reduce_stats(
    const float* __restrict__ Cz, float* __restrict__ C,
    const float* __restrict__ bias_l, float* __restrict__ st, int M) {
    const int t = threadIdx.x;
    const int m0 = blockIdx.x * 16;
    const size_t zstride = (size_t)M * BATCH;
    float s0 = 0.f, q0 = 0.f, s1 = 0.f, q1 = 0.f;
#pragma unroll 4
    for (int m = 0; m < 16; ++m) {
        const size_t off = (size_t)(m0 + m) * BATCH + t * 2;
        float2 v = *(const float2*)(Cz + off);
        const float2 v1 = *(const float2*)(Cz + zstride + off);
        const float2 v2 = *(const float2*)(Cz + 2 * zstride + off);
        const float2 v3 = *(const float2*)(Cz + 3 * zstride + off);
        const float bv = bias_l[m0 + m];
        v.x += v1.x + v2.x + v3.x + bv;
        v.y += v1.y + v2.y + v3.y + bv;
        *(float2*)(C + off) = v;
        s0 += v.x; q0 += v.x * v.x;
        s1 += v.y; q1 += v.y * v.y;
    }
    atomicAdd(&st[t * 2], s0);
    atomicAdd(&st[t * 2 + 1], s1);
    atomicAdd(&st[BATCH + t * 2], q0);
    atomicAdd(&st[BATCH + t * 2 + 1], q1);
}

// ---------------------------------------------------------------------------
// LN+ReLU apply + transpose: act fp32 [M][512] -> actb bf16 [512][M].
__global__ __launch_bounds__(256) void lnapply(
    const float* __restrict__ act, const float* __restrict__ st,
    const float* __restrict__ gamma_l, const float* __restrict__ beta_l,
    u16* __restrict__ actb, int M, float invDim) {
    __shared__ u16 tile[32][40];
    const int t = threadIdx.x;
    const int m0 = blockIdx.x * 32, n0 = blockIdx.y * 32;
    {
        const int m = t >> 3, nq = t & 7;
        const float4 v = *(const float4*)(act + (size_t)(m0 + m) * BATCH + n0 + nq * 4);
        const float g = gamma_l[m0 + m], bt = beta_l[m0 + m];
        const float4 s1 = *(const float4*)(st + n0 + nq * 4);
        const float4 s2 = *(const float4*)(st + BATCH + n0 + nq * 4);
        float mn[4], rs[4];
        mn[0] = s1.x * invDim; mn[1] = s1.y * invDim; mn[2] = s1.z * invDim; mn[3] = s1.w * invDim;
        rs[0] = rsqrtf(s2.x * invDim - mn[0] * mn[0] + EPS);
        rs[1] = rsqrtf(s2.y * invDim - mn[1] * mn[1] + EPS);
        rs[2] = rsqrtf(s2.z * invDim - mn[2] * mn[2] + EPS);
        rs[3] = rsqrtf(s2.w * invDim - mn[3] * mn[3] + EPS);
        const float vv[4] = {v.x, v.y, v.z, v.w};
#pragma unroll
        for (int i = 0; i < 4; ++i)
            tile[nq * 4 + i][m] = f2bf(fmaxf(fmaf(g * (vv[i] - mn[i]), rs[i], bt), 0.0f));
    }
    __syncthreads();
    {
        const int n = t >> 3, mq = t & 7;
        u16 o[4];
#pragma unroll
        for (int i = 0; i < 4; ++i) o[i] = tile[n][mq * 4 + i];
        *(uint2*)(actb + (size_t)(n0 + n) * M + m0 + mq * 4) = *(const uint2*)o;
    }
}

// ---------------------------------------------------------------------------
// Output layer: 2 nodes from post-LN bf16 actb3 [512][512]. grid 4 x 256.
__global__ __launch_bounds__(256) void outk(
    const u16* __restrict__ actb3, const float* __restrict__ weight,
    const int* __restrict__ edge_src, const float* __restrict__ bias,
    float* __restrict__ out) {
    __shared__ float w_s[256]; __shared__ int s_s[256];
    const int t = threadIdx.x;
    w_s[t] = weight[458752 + t];
    s_s[t] = edge_src[458752 + t] - 7168;
    __syncthreads();
    const int g = blockIdx.x * 256 + t;   // 0..1023
    const int b = g >> 1, j = g & 1;
    const u16* rowp = actb3 + (size_t)b * 512;
    const int kb = j * FAN_IN;
    float acc = 0.f;
#pragma unroll 8
    for (int k = 0; k < FAN_IN; ++k)
        acc += w_s[kb + k] * bf2f(rowp[s_s[kb + k]]);
    out[(size_t)b * 2 + j] = acc + bias[3584 + j];
}

// ---------------------------------------------------------------------------
extern "C" void kernel_launch(void* const* d_in, const int* in_sizes, int n_in,
                              void* d_out, int out_size, void* d_ws, size_t ws_size,
                              hipStream_t stream) {
    const float* x        = (const float*)d_in[0];
    const float* weight   = (const float*)d_in[1];
    const float* bias     = (const float*)d_in[2];
    const float* ln_gamma = (const float*)d_in[3];
    const float* ln_beta  = (const float*)d_in[4];
    const int*   edge_src = (const int*)d_in[5];
    float* out = (float*)d_out;

    // ws layout (fp32 units first):
    float* Cz1   = (float*)d_ws;                       // 4 x [2048 x 512]
    float* Cz2   = Cz1 + (size_t)4 * 2048 * 512;       // 4 x [1024 x 512]
    float* Cz3   = Cz2 + (size_t)4 * 1024 * 512;       // 4 x [512 x 512]
    float* C1    = Cz3 + (size_t)4 * 512 * 512;        // [2048 x 512]
    float* C2    = C1 + (size_t)2048 * 512;            // [1024 x 512]
    float* C3    = C2 + (size_t)1024 * 512;            // [512 x 512]
    float* stats = C3 + (size_t)512 * 512;             // 3 x 1024
    u16*   xb    = (u16*)(stats + 3072);               // [512 x 4096] bf16
    u16*   actb1 = xb + (size_t)512 * 4096;            // [512 x 2048]
    u16*   actb2 = actb1 + (size_t)512 * 2048;         // [512 x 1024]
    u16*   actb3 = actb2 + (size_t)512 * 1024;         // [512 x 512]
    u16*   Wd    = actb3 + (size_t)512 * 512;          // 11534336 bf16
    float* st1 = stats, *st2 = stats + 1024, *st3 = stats + 2048;

    prep<<<4097, 256, 0, stream>>>(weight, edge_src, x, Wd, xb, stats);

    // G1: [2048x4096] x xb^T, K-split 4 -> Cz1
    gemm_bt<<<dim3(32, 8, 4), 256, 0, stream>>>(Wd, xb, Cz1, 2048, 4096, 1024);
    reduce_stats<<<128, 256, 0, stream>>>(Cz1, C1, bias, st1, 2048);
    lnapply<<<dim3(64, 16), 256, 0, stream>>>(C1, st1, ln_gamma, ln_beta,
                                              actb1, 2048, 1.0f / 2048.0f);
    // G2: [1024x2048] x actb1^T
    gemm_bt<<<dim3(16, 8, 4), 256, 0, stream>>>(Wd + 8388608, actb1, Cz2,
                                                1024, 2048, 512);
    reduce_stats<<<64, 256, 0, stream>>>(Cz2, C2, bias + 2048, st2, 1024);
    lnapply<<<dim3(32, 16), 256, 0, stream>>>(C2, st2, ln_gamma + 2048,
                                              ln_beta + 2048, actb2, 1024,
                                              1.0f / 1024.0f);
    // G3: [512x1024] x actb2^T
    gemm_bt<<<dim3(8, 8, 4), 256, 0, stream>>>(Wd + 10485760, actb2, Cz3,
                                               512, 1024, 256);
    reduce_stats<<<32, 256, 0, stream>>>(Cz3, C3, bias + 3072, st3, 512);
    lnapply<<<dim3(16, 16), 256, 0, stream>>>(C3, st3, ln_gamma + 3072,
                                              ln_beta + 3072, actb3, 512,
                                              1.0f / 512.0f);
    // Output layer -> d_out [512, 2]
    outk<<<4, 256, 0, stream>>>(actb3, weight, edge_src, bias, out);
}